// Round 5
// baseline (1244.686 us; speedup 1.0000x reference)
//
#include <hip/hip_runtime.h>
#include <hip/hip_bf16.h>

#define BB 4
#define NN 2048
#define DD 128
#define HH 4
#define LOG2E 1.4426950408889634f
#define NEG_BIG (-1e30f)

// Established: float inputs are fp32 (R2 NaN fingerprint: fp32-read-as-bf16
// guarantees NaN, bf16-read-as-fp32 gives finite shuffle). This round's
// theory: OUTPUTS are fp32 too (reference returns fp32; the "bf16" in the
// test label is hard-coded text). R3/R4's deterministic absmax 0.397 matches
// the "bf16-written-into-fp32-buffer" shuffle signature max|ref[j]-ref[2j+1]|.

// ---------------------------------------------------------------------------
// Kernel A: wsv[h][i] = sum_o W[h,i,o]*a[h,o]; wdv likewise with a[h,D+o].
// ---------------------------------------------------------------------------
__global__ __launch_bounds__(128) void k_wvec(const float* __restrict__ W,
                                              const float* __restrict__ a,
                                              float* __restrict__ wsv,
                                              float* __restrict__ wdv) {
    int h = blockIdx.x;
    int i = threadIdx.x;
    const float* Wr  = W + (h * DD + i) * DD;
    const float* as_ = a + h * 2 * DD;
    const float* ad_ = as_ + DD;
    float s = 0.f, d = 0.f;
    for (int o = 0; o < DD; ++o) {
        float w = Wr[o];
        s += w * as_[o];
        d += w * ad_[o];
    }
    wsv[h * DD + i] = s;
    wdv[h * DD + i] = d;
}

// ---------------------------------------------------------------------------
// Kernel B: s[b,h,n] = x[b,n,:] . wsv[h]; d likewise. 64 rows/block.
// ---------------------------------------------------------------------------
__global__ __launch_bounds__(256) void k_sd(const float* __restrict__ x,
                                            const float* __restrict__ wsv,
                                            const float* __restrict__ wdv,
                                            float* __restrict__ s_out,
                                            float* __restrict__ d_out_) {
    __shared__ float xs[64 * 129];
    __shared__ float ws[4 * 129], wd[4 * 129];
    int tid = threadIdx.x;
    int b  = blockIdx.x / (NN / 64);
    int nb = (blockIdx.x % (NN / 64)) * 64;
    for (int idx = tid; idx < HH * DD; idx += 256) {
        ws[(idx >> 7) * 129 + (idx & 127)] = wsv[idx];
        wd[(idx >> 7) * 129 + (idx & 127)] = wdv[idx];
    }
    for (int idx = tid; idx < 64 * 128; idx += 256) {
        int r = idx >> 7, c = idx & 127;
        xs[r * 129 + c] = x[((size_t)b * NN + nb + r) * DD + c];
    }
    __syncthreads();
    int h = tid & 3, r = tid >> 2;   // 4 heads x 64 rows
    float sv = 0.f, dv = 0.f;
#pragma unroll 8
    for (int i = 0; i < DD; ++i) {
        float xv = xs[r * 129 + i];
        sv += xv * ws[h * 129 + i];
        dv += xv * wd[h * 129 + i];
    }
    int n = nb + r;
    s_out[(b * HH + h) * NN + n] = sv;
    d_out_[(b * HH + h) * NN + n] = dv;
}

// ---------------------------------------------------------------------------
// Kernel H: h[b,h,n,o] = sum_i x[b,n,i]*W[h,i,o], fp32 out. 32 rows/block.
// ---------------------------------------------------------------------------
__global__ __launch_bounds__(256) void k_h(const float* __restrict__ x,
                                           const float* __restrict__ W,
                                           float* __restrict__ h_scr) {
    __shared__ float xs[32 * 129];
    int tid = threadIdx.x;
    int bh = blockIdx.x / (NN / 32);
    int nb = (blockIdx.x % (NN / 32)) * 32;
    int b = bh >> 2, h = bh & 3;
    for (int idx = tid; idx < 32 * 128; idx += 256) {
        int r = idx >> 7, c = idx & 127;
        xs[r * 129 + c] = x[((size_t)b * NN + nb + r) * DD + c];
    }
    __syncthreads();
    int o = tid & 127, rh = tid >> 7;
    float acc[16];
#pragma unroll
    for (int j = 0; j < 16; ++j) acc[j] = 0.f;
    for (int i = 0; i < DD; ++i) {
        float wv = W[(h * DD + i) * DD + o];
#pragma unroll
        for (int j = 0; j < 16; ++j) acc[j] += xs[(rh * 16 + j) * 129 + i] * wv;
    }
#pragma unroll
    for (int j = 0; j < 16; ++j)
        h_scr[((size_t)bh * NN + nb + rh * 16 + j) * DD + o] = acc[j];
}

// ---------------------------------------------------------------------------
// Kernel S: online softmax stats per (b,n) row for all 4 heads. NaN-free.
// ---------------------------------------------------------------------------
__global__ __launch_bounds__(256) void k_stats(const int* __restrict__ adj,
                                               const float* __restrict__ s_in,
                                               const float* __restrict__ d_in_,
                                               float* __restrict__ M_out,
                                               float* __restrict__ Li_out) {
    __shared__ float Ms[4][256];
    __shared__ float Ls[4][256];
    int tid = threadIdx.x;
    int b = blockIdx.x / NN, n = blockIdx.x % NN;
    float sv[4];
#pragma unroll
    for (int h = 0; h < 4; ++h) sv[h] = s_in[(b * HH + h) * NN + n];
    float M[4], L[4];
#pragma unroll
    for (int h = 0; h < 4; ++h) { M[h] = NEG_BIG; L[h] = 0.f; }
    const int* arow = adj + ((size_t)b * NN + n) * NN;
    for (int m = tid; m < NN; m += 256) {
        int av = arow[m];
        if (av != 0) {
#pragma unroll
            for (int h = 0; h < 4; ++h) {
                float t = sv[h] + d_in_[(b * HH + h) * NN + m];
                float v = t > 0.f ? t : 0.2f * t;
                if (v <= M[h]) {
                    L[h] += exp2f((v - M[h]) * LOG2E);
                } else {
                    L[h] = L[h] * exp2f((M[h] - v) * LOG2E) + 1.f;
                    M[h] = v;
                }
            }
        }
    }
#pragma unroll
    for (int h = 0; h < 4; ++h) { Ms[h][tid] = M[h]; Ls[h][tid] = L[h]; }
    for (int off = 128; off >= 1; off >>= 1) {
        __syncthreads();
        if (tid < off) {
#pragma unroll
            for (int h = 0; h < 4; ++h) {
                float Ma = Ms[h][tid],        La = Ls[h][tid];
                float Mb = Ms[h][tid + off],  Lb = Ls[h][tid + off];
                float Mx = fmaxf(Ma, Mb);
                float Lx = La * exp2f((Ma - Mx) * LOG2E)
                         + Lb * exp2f((Mb - Mx) * LOG2E);
                Ms[h][tid] = Mx; Ls[h][tid] = Lx;
            }
        }
    }
    __syncthreads();
    if (tid == 0) {
#pragma unroll
        for (int h = 0; h < 4; ++h) {
            float L0 = Ls[h][0];
            M_out[(b * HH + h) * NN + n]  = Ms[h][0];
            Li_out[(b * HH + h) * NN + n] = L0 > 0.f ? 1.f / L0 : 0.f;
        }
    }
}

// ---------------------------------------------------------------------------
// Kernel 3: alpha@h accumulation only. Per (b,h,64-row tile), m-chunks of 32:
// recompute alpha tile in LDS, FMA into 8x8 register tiles.
// ---------------------------------------------------------------------------
__global__ __launch_bounds__(128) void k_attn2(const int* __restrict__ adj,
                                               const float* __restrict__ s_in,
                                               const float* __restrict__ d_in_,
                                               const float* __restrict__ M_in,
                                               const float* __restrict__ Li_in,
                                               const float* __restrict__ h_scr,
                                               float* __restrict__ out_scr) {
    __shared__ float al[64 * 33];
    __shared__ float hs[32 * 132];
    __shared__ float srow[64], Mrow[64], Lirow[64];
    __shared__ float dch[32];
    int tid = threadIdx.x;
    int bh = blockIdx.x >> 5;
    int nb = (blockIdx.x & 31) * 64;
    int b = bh >> 2;
    if (tid < 64) {
        srow[tid]  = s_in[bh * NN + nb + tid];
        Mrow[tid]  = M_in[bh * NN + nb + tid];
        Lirow[tid] = Li_in[bh * NN + nb + tid];
    }
    float acc[8][8];
#pragma unroll
    for (int j = 0; j < 8; ++j)
#pragma unroll
        for (int k = 0; k < 8; ++k) acc[j][k] = 0.f;

    int ml = tid & 31, ng0 = tid >> 5;
    int og = tid & 15, ng = tid >> 4;
    int o0 = og * 8, n0 = ng * 8;

    for (int mb = 0; mb < NN; mb += 32) {
        if (tid < 32) dch[tid] = d_in_[bh * NN + mb + tid];
        __syncthreads();
#pragma unroll
        for (int i = 0; i < 16; ++i) {
            int nl = ng0 + i * 4;
            int n = nb + nl;
            int av = adj[((size_t)b * NN + n) * NN + mb + ml];
            float val = 0.f;
            if (av != 0) {
                float t = srow[nl] + dch[ml];
                float v = t > 0.f ? t : 0.2f * t;
                val = exp2f((v - Mrow[nl]) * LOG2E) * Lirow[nl];
            }
            al[nl * 33 + ml] = val;
        }
        for (int idx = tid; idx < 32 * 128; idx += 128) {
            int mr = idx >> 7, c = idx & 127;
            hs[mr * 132 + c] = h_scr[((size_t)bh * NN + mb + mr) * DD + c];
        }
        __syncthreads();
#pragma unroll 4
        for (int m = 0; m < 32; ++m) {
            const float4* hp = reinterpret_cast<const float4*>(&hs[m * 132 + o0]);
            float4 h0 = hp[0], h1 = hp[1];
            float hv[8] = {h0.x, h0.y, h0.z, h0.w, h1.x, h1.y, h1.z, h1.w};
#pragma unroll
            for (int j = 0; j < 8; ++j) {
                float av_ = al[(n0 + j) * 33 + m];
#pragma unroll
                for (int k = 0; k < 8; ++k) acc[j][k] += av_ * hv[k];
            }
        }
    }
#pragma unroll
    for (int j = 0; j < 8; ++j) {
        float4 v0 = make_float4(acc[j][0], acc[j][1], acc[j][2], acc[j][3]);
        float4 v1 = make_float4(acc[j][4], acc[j][5], acc[j][6], acc[j][7]);
        float4* op = reinterpret_cast<float4*>(
            &out_scr[((size_t)bh * NN + nb + n0 + j) * DD + o0]);
        op[0] = v0;
        op[1] = v1;
    }
}

// ---------------------------------------------------------------------------
// Kernel 4: output[b,n,o] = concat_h(out_scr) @ Wp + bias, fp32 store.
// ---------------------------------------------------------------------------
__global__ __launch_bounds__(256) void k_proj(const float* __restrict__ out_scr,
                                              const float* __restrict__ Wp,
                                              const float* __restrict__ bias,
                                              float* __restrict__ out) {
    __shared__ float cs[16 * 512];
    int tid = threadIdx.x;
    int b  = blockIdx.x / (NN / 16);
    int nb = (blockIdx.x % (NN / 16)) * 16;
    for (int idx = tid; idx < 16 * 512; idx += 256) {
        int r = idx >> 9, c = idx & 511;
        int hh = c >> 7, oo = c & 127;
        cs[idx] = out_scr[((size_t)(b * HH + hh) * NN + nb + r) * DD + oo];
    }
    __syncthreads();
    int o = tid & 127, rg = tid >> 7;
    float bv = bias[o];
    float acc[8];
#pragma unroll
    for (int j = 0; j < 8; ++j) acc[j] = bv;
    for (int k = 0; k < 512; ++k) {
        float w = Wp[k * DD + o];
#pragma unroll
        for (int j = 0; j < 8; ++j) acc[j] += cs[(rg * 8 + j) * 512 + k] * w;
    }
#pragma unroll
    for (int j = 0; j < 8; ++j)
        out[((size_t)b * NN + nb + rg * 8 + j) * DD + o] = acc[j];
}

// ---------------------------------------------------------------------------
// Kernel 5 (LAST): write final fp32 alpha over the (now-consumed) scratch.
// ---------------------------------------------------------------------------
__global__ __launch_bounds__(256) void k_alpha(const int* __restrict__ adj,
                                               const float* __restrict__ s_in,
                                               const float* __restrict__ d_in_,
                                               const float* __restrict__ M_in,
                                               const float* __restrict__ Li_in,
                                               float* __restrict__ alpha_out) {
    int tid = threadIdx.x;
    int b = blockIdx.x / NN, n = blockIdx.x % NN;
    float sv[4], Mv[4], Lv[4];
#pragma unroll
    for (int h = 0; h < 4; ++h) {
        sv[h] = s_in[(b * HH + h) * NN + n];
        Mv[h] = M_in[(b * HH + h) * NN + n];
        Lv[h] = Li_in[(b * HH + h) * NN + n];
    }
    const int* arow = adj + ((size_t)b * NN + n) * NN;
    for (int m = tid; m < NN; m += 256) {
        int av = arow[m];
#pragma unroll
        for (int h = 0; h < 4; ++h) {
            float val = 0.f;
            if (av != 0) {
                float t = sv[h] + d_in_[(b * HH + h) * NN + m];
                float v = t > 0.f ? t : 0.2f * t;
                val = exp2f((v - Mv[h]) * LOG2E) * Lv[h];
            }
            alpha_out[((size_t)(b * HH + h) * NN + n) * NN + m] = val;
        }
    }
}

// ---------------------------------------------------------------------------
extern "C" void kernel_launch(void* const* d_in, const int* in_sizes, int n_in,
                              void* d_out, int out_size, void* d_ws, size_t ws_size,
                              hipStream_t stream) {
    const float* x    = (const float*)d_in[0];
    const int*   adj  = (const int*)d_in[1];
    const float* W    = (const float*)d_in[2];
    const float* a    = (const float*)d_in[3];
    const float* Wp   = (const float*)d_in[4];
    const float* bias = (const float*)d_in[5];

    float* out       = (float*)d_out;
    float* alpha_out = out + (size_t)BB * NN * DD;

    // Scratch inside the fp32 alpha region (268 MB; written LAST by k_alpha):
    //   h_scr   fp32 [B*H*N*D] at alpha floats [0, 4M)
    //   out_scr fp32 [B*H*N*D] at alpha floats [4M, 8M)
    float* h_scr   = alpha_out;
    float* out_scr = h_scr + (size_t)BB * HH * NN * DD;

    // d_ws: only the small stat vectors (528 KB total).
    float* ws  = (float*)d_ws;
    float* wsv = ws;                      // 512 f
    float* wdv = wsv + HH * DD;           // 512 f
    float* s_  = wdv + HH * DD;           // 32768 f
    float* d_  = s_ + BB * HH * NN;       // 32768 f
    float* M_  = d_ + BB * HH * NN;       // 32768 f
    float* Li_ = M_ + BB * HH * NN;       // 32768 f

    k_wvec<<<HH, 128, 0, stream>>>(W, a, wsv, wdv);
    k_sd<<<BB * NN / 64, 256, 0, stream>>>(x, wsv, wdv, s_, d_);
    k_h<<<BB * HH * (NN / 32), 256, 0, stream>>>(x, W, h_scr);
    k_stats<<<BB * NN, 256, 0, stream>>>(adj, s_, d_, M_, Li_);
    k_attn2<<<BB * HH * (NN / 64), 128, 0, stream>>>(adj, s_, d_, M_, Li_,
                                                     h_scr, out_scr);
    k_proj<<<BB * (NN / 16), 256, 0, stream>>>(out_scr, Wp, bias, out);
    k_alpha<<<BB * NN, 256, 0, stream>>>(adj, s_, d_, M_, Li_, alpha_out);
}

// Round 6
// 628.474 us; speedup vs baseline: 1.9805x; 1.9805x over previous
//
#include <hip/hip_runtime.h>
#include <hip/hip_bf16.h>

#define BB 4
#define NN 2048
#define DD 128
#define HH 4
#define LOG2E 1.4426950408889634f
#define NEG_BIG (-1e30f)

typedef __attribute__((ext_vector_type(8))) short bf16x8;   // 8 bf16 in 4 VGPRs
typedef __attribute__((ext_vector_type(4))) float f32x4;    // MFMA accumulator

__device__ __forceinline__ unsigned short f2bf(float f) {
    union { float f; unsigned int u; } v; v.f = f;
    unsigned int r = v.u + 0x7FFF + ((v.u >> 16) & 1);      // round-nearest-even
    return (unsigned short)(r >> 16);
}

// ---------------------------------------------------------------------------
// Kernel A: wsv[h][i] = sum_o W[h,i,o]*a[h,o]; wdv likewise with a[h,D+o].
// ---------------------------------------------------------------------------
__global__ __launch_bounds__(128) void k_wvec(const float* __restrict__ W,
                                              const float* __restrict__ a,
                                              float* __restrict__ wsv,
                                              float* __restrict__ wdv) {
    int h = blockIdx.x;
    int i = threadIdx.x;
    const float* Wr  = W + (h * DD + i) * DD;
    const float* as_ = a + h * 2 * DD;
    const float* ad_ = as_ + DD;
    float s = 0.f, d = 0.f;
    for (int o = 0; o < DD; ++o) {
        float w = Wr[o];
        s += w * as_[o];
        d += w * ad_[o];
    }
    wsv[h * DD + i] = s;
    wdv[h * DD + i] = d;
}

// ---------------------------------------------------------------------------
// Kernel B: s[b,h,n] = x[b,n,:] . wsv[h]; d likewise. 64 rows/block.
// ---------------------------------------------------------------------------
__global__ __launch_bounds__(256) void k_sd(const float* __restrict__ x,
                                            const float* __restrict__ wsv,
                                            const float* __restrict__ wdv,
                                            float* __restrict__ s_out,
                                            float* __restrict__ d_out_) {
    __shared__ float xs[64 * 129];
    __shared__ float ws[4 * 129], wd[4 * 129];
    int tid = threadIdx.x;
    int b  = blockIdx.x / (NN / 64);
    int nb = (blockIdx.x % (NN / 64)) * 64;
    for (int idx = tid; idx < HH * DD; idx += 256) {
        ws[(idx >> 7) * 129 + (idx & 127)] = wsv[idx];
        wd[(idx >> 7) * 129 + (idx & 127)] = wdv[idx];
    }
    for (int idx = tid; idx < 64 * 128; idx += 256) {
        int r = idx >> 7, c = idx & 127;
        xs[r * 129 + c] = x[((size_t)b * NN + nb + r) * DD + c];
    }
    __syncthreads();
    int h = tid & 3, r = tid >> 2;
    float sv = 0.f, dv = 0.f;
#pragma unroll 8
    for (int i = 0; i < DD; ++i) {
        float xv = xs[r * 129 + i];
        sv += xv * ws[h * 129 + i];
        dv += xv * wd[h * 129 + i];
    }
    int n = nb + r;
    s_out[(b * HH + h) * NN + n] = sv;
    d_out_[(b * HH + h) * NN + n] = dv;
}

// ---------------------------------------------------------------------------
// Kernel H: h[b,h,n,o] = sum_i x[b,n,i]*W[h,i,o]; stored TRANSPOSED as bf16:
// hT[bh][o][n] (n contiguous) — the MFMA B-operand layout for k_attn_mfma.
// ---------------------------------------------------------------------------
__global__ __launch_bounds__(256) void k_h(const float* __restrict__ x,
                                           const float* __restrict__ W,
                                           unsigned short* __restrict__ hT) {
    __shared__ float xs[32 * 129];
    int tid = threadIdx.x;
    int bh = blockIdx.x / (NN / 32);
    int nb = (blockIdx.x % (NN / 32)) * 32;
    int b = bh >> 2, h = bh & 3;
    for (int idx = tid; idx < 32 * 128; idx += 256) {
        int r = idx >> 7, c = idx & 127;
        xs[r * 129 + c] = x[((size_t)b * NN + nb + r) * DD + c];
    }
    __syncthreads();
    int o = tid & 127, rh = tid >> 7;   // rh in {0,1}: 16 n-rows each
    float acc[16];
#pragma unroll
    for (int j = 0; j < 16; ++j) acc[j] = 0.f;
    for (int i = 0; i < DD; ++i) {
        float wv = W[(h * DD + i) * DD + o];
#pragma unroll
        for (int j = 0; j < 16; ++j) acc[j] += xs[(rh * 16 + j) * 129 + i] * wv;
    }
    bf16x8 p0, p1;
#pragma unroll
    for (int j = 0; j < 8; ++j) { p0[j] = (short)f2bf(acc[j]); p1[j] = (short)f2bf(acc[8 + j]); }
    unsigned short* dst = hT + ((size_t)bh * DD + o) * NN + nb + rh * 16;
    *(bf16x8*)dst = p0;
    *(bf16x8*)(dst + 8) = p1;
}

// ---------------------------------------------------------------------------
// Kernel S: online softmax stats per (b,n) row for all 4 heads. NaN-free.
// (unchanged from the passing R5 version)
// ---------------------------------------------------------------------------
__global__ __launch_bounds__(256) void k_stats(const int* __restrict__ adj,
                                               const float* __restrict__ s_in,
                                               const float* __restrict__ d_in_,
                                               float* __restrict__ M_out,
                                               float* __restrict__ Li_out) {
    __shared__ float Ms[4][256];
    __shared__ float Ls[4][256];
    int tid = threadIdx.x;
    int b = blockIdx.x / NN, n = blockIdx.x % NN;
    float sv[4];
#pragma unroll
    for (int h = 0; h < 4; ++h) sv[h] = s_in[(b * HH + h) * NN + n];
    float M[4], L[4];
#pragma unroll
    for (int h = 0; h < 4; ++h) { M[h] = NEG_BIG; L[h] = 0.f; }
    const int* arow = adj + ((size_t)b * NN + n) * NN;
    for (int m = tid; m < NN; m += 256) {
        int av = arow[m];
        if (av != 0) {
#pragma unroll
            for (int h = 0; h < 4; ++h) {
                float t = sv[h] + d_in_[(b * HH + h) * NN + m];
                float v = t > 0.f ? t : 0.2f * t;
                if (v <= M[h]) {
                    L[h] += exp2f((v - M[h]) * LOG2E);
                } else {
                    L[h] = L[h] * exp2f((M[h] - v) * LOG2E) + 1.f;
                    M[h] = v;
                }
            }
        }
    }
#pragma unroll
    for (int h = 0; h < 4; ++h) { Ms[h][tid] = M[h]; Ls[h][tid] = L[h]; }
    for (int off = 128; off >= 1; off >>= 1) {
        __syncthreads();
        if (tid < off) {
#pragma unroll
            for (int h = 0; h < 4; ++h) {
                float Ma = Ms[h][tid],        La = Ls[h][tid];
                float Mb = Ms[h][tid + off],  Lb = Ls[h][tid + off];
                float Mx = fmaxf(Ma, Mb);
                float Lx = La * exp2f((Ma - Mx) * LOG2E)
                         + Lb * exp2f((Mb - Mx) * LOG2E);
                Ms[h][tid] = Mx; Ls[h][tid] = Lx;
            }
        }
    }
    __syncthreads();
    if (tid == 0) {
#pragma unroll
        for (int h = 0; h < 4; ++h) {
            float L0 = Ls[h][0];
            M_out[(b * HH + h) * NN + n]  = Ms[h][0];
            Li_out[(b * HH + h) * NN + n] = L0 > 0.f ? 1.f / L0 : 0.f;
        }
    }
}

// ---------------------------------------------------------------------------
// Kernel 3 (MFMA): per (b,h,64-n-tile): C[64n][128o] = alpha @ h.
// m-stages of 128: adj tile -> bf16 alpha in LDS (A-layout), hT chunk staged
// to LDS (B-layout), 4 waves x 8 o-tiles x 4 k-steps of mfma_f32_16x16x32_bf16.
// ---------------------------------------------------------------------------
__global__ __launch_bounds__(256) void k_attn_mfma(const int* __restrict__ adj,
                                                   const float* __restrict__ s_in,
                                                   const float* __restrict__ d_in_,
                                                   const float* __restrict__ M_in,
                                                   const float* __restrict__ Li_in,
                                                   const unsigned short* __restrict__ hT,
                                                   float* __restrict__ out_scr) {
    __shared__ unsigned short al_lds[64 * 136];    // alpha tile, +8 bf16 pad
    __shared__ unsigned short hT_lds[128 * 136];   // h chunk (o-major), +8 pad
    __shared__ float dall[NN];
    __shared__ float srow[64], Mrow[64], Lirow[64];
    int tid = threadIdx.x;
    int bh = blockIdx.x >> 5;
    int nb = (blockIdx.x & 31) * 64;
    int b = bh >> 2;

    if (tid < 64) {
        srow[tid]  = s_in[bh * NN + nb + tid];
        Mrow[tid]  = M_in[bh * NN + nb + tid];
        Lirow[tid] = Li_in[bh * NN + nb + tid];
    }
    for (int i = tid; i < NN / 4; i += 256)
        ((float4*)dall)[i] = ((const float4*)(d_in_ + (size_t)bh * NN))[i];
    __syncthreads();

    // phase-A mapping: thread -> (n row, 32-m segment)
    int an = tid >> 2, mseg = (tid & 3) * 32;
    float sn = srow[an], Mn = Mrow[an], Lin = Lirow[an];
    const int* arow = adj + ((size_t)b * NN + nb + an) * NN;
    // phase-B mapping: thread -> (o row, 64-m half)
    int ho = tid >> 1, hhalf = (tid & 1) * 64;
    const unsigned short* hrow = hT + ((size_t)bh * DD + ho) * NN;
    // phase-C mapping: wave/lane
    int l = tid & 63, w = tid >> 6, col = l & 15, quad = l >> 4;

    f32x4 acc[8];
#pragma unroll
    for (int ot = 0; ot < 8; ++ot) acc[ot] = (f32x4){0.f, 0.f, 0.f, 0.f};

    for (int mb = 0; mb < NN; mb += 128) {
        __syncthreads();   // prev-stage MFMA reads complete before overwrite
        // --- phase A: alpha tile (bf16) into LDS A-layout ---
        const int4* ap = (const int4*)(arow + mb + mseg);
#pragma unroll
        for (int g = 0; g < 4; ++g) {
            int4 a0 = ap[2 * g], a1 = ap[2 * g + 1];
            float4 d0 = *(const float4*)&dall[mb + mseg + g * 8];
            float4 d1 = *(const float4*)&dall[mb + mseg + g * 8 + 4];
            int   av[8] = {a0.x, a0.y, a0.z, a0.w, a1.x, a1.y, a1.z, a1.w};
            float dv[8] = {d0.x, d0.y, d0.z, d0.w, d1.x, d1.y, d1.z, d1.w};
            bf16x8 pk;
#pragma unroll
            for (int j = 0; j < 8; ++j) {
                float t = sn + dv[j];
                float v = t > 0.f ? t : 0.2f * t;
                float e = (av[j] != 0) ? exp2f((v - Mn) * LOG2E) * Lin : 0.f;
                pk[j] = (short)f2bf(e);
            }
            *(bf16x8*)&al_lds[an * 136 + mseg + g * 8] = pk;
        }
        // --- phase B: stage hT chunk [128 o][128 m] ---
#pragma unroll
        for (int q = 0; q < 8; ++q) {
            bf16x8 hv = *(const bf16x8*)(hrow + mb + hhalf + q * 8);
            *(bf16x8*)&hT_lds[ho * 136 + hhalf + q * 8] = hv;
        }
        __syncthreads();
        // --- phase C: MFMA ---
#pragma unroll
        for (int k = 0; k < 4; ++k) {
            bf16x8 af = *(const bf16x8*)&al_lds[(w * 16 + col) * 136 + k * 32 + quad * 8];
#pragma unroll
            for (int ot = 0; ot < 8; ++ot) {
                bf16x8 bfv = *(const bf16x8*)&hT_lds[(ot * 16 + col) * 136 + k * 32 + quad * 8];
                acc[ot] = __builtin_amdgcn_mfma_f32_16x16x32_bf16(af, bfv, acc[ot], 0, 0, 0);
            }
        }
    }
    // epilogue: C/D layout col=lane&15, row=quad*4+reg
#pragma unroll
    for (int ot = 0; ot < 8; ++ot)
#pragma unroll
        for (int r = 0; r < 4; ++r)
            out_scr[((size_t)bh * NN + nb + w * 16 + quad * 4 + r) * DD + ot * 16 + col] =
                acc[ot][r];
}

// ---------------------------------------------------------------------------
// Kernel 4: output[b,n,o] = concat_h(out_scr) @ Wp + bias, fp32 store.
// ---------------------------------------------------------------------------
__global__ __launch_bounds__(256) void k_proj(const float* __restrict__ out_scr,
                                              const float* __restrict__ Wp,
                                              const float* __restrict__ bias,
                                              float* __restrict__ out) {
    __shared__ float cs[16 * 512];
    int tid = threadIdx.x;
    int b  = blockIdx.x / (NN / 16);
    int nb = (blockIdx.x % (NN / 16)) * 16;
    for (int idx = tid; idx < 16 * 512; idx += 256) {
        int r = idx >> 9, c = idx & 511;
        int hh = c >> 7, oo = c & 127;
        cs[idx] = out_scr[((size_t)(b * HH + hh) * NN + nb + r) * DD + oo];
    }
    __syncthreads();
    int o = tid & 127, rg = tid >> 7;
    float bv = bias[o];
    float acc[8];
#pragma unroll
    for (int j = 0; j < 8; ++j) acc[j] = bv;
    for (int k = 0; k < 512; ++k) {
        float w = Wp[k * DD + o];
#pragma unroll
        for (int j = 0; j < 8; ++j) acc[j] += cs[(rg * 8 + j) * 512 + k] * w;
    }
#pragma unroll
    for (int j = 0; j < 8; ++j)
        out[((size_t)b * NN + nb + rg * 8 + j) * DD + o] = acc[j];
}

// ---------------------------------------------------------------------------
// Kernel 5 (LAST): write final fp32 alpha over the (now-consumed) scratch.
// ---------------------------------------------------------------------------
__global__ __launch_bounds__(256) void k_alpha(const int* __restrict__ adj,
                                               const float* __restrict__ s_in,
                                               const float* __restrict__ d_in_,
                                               const float* __restrict__ M_in,
                                               const float* __restrict__ Li_in,
                                               float* __restrict__ alpha_out) {
    int tid = threadIdx.x;
    int b = blockIdx.x / NN, n = blockIdx.x % NN;
    float sv[4], Mv[4], Lv[4];
#pragma unroll
    for (int h = 0; h < 4; ++h) {
        sv[h] = s_in[(b * HH + h) * NN + n];
        Mv[h] = M_in[(b * HH + h) * NN + n];
        Lv[h] = Li_in[(b * HH + h) * NN + n];
    }
    const int* arow = adj + ((size_t)b * NN + n) * NN;
    for (int m = tid; m < NN; m += 256) {
        int av = arow[m];
#pragma unroll
        for (int h = 0; h < 4; ++h) {
            float val = 0.f;
            if (av != 0) {
                float t = sv[h] + d_in_[(b * HH + h) * NN + m];
                float v = t > 0.f ? t : 0.2f * t;
                val = exp2f((v - Mv[h]) * LOG2E) * Lv[h];
            }
            alpha_out[((size_t)(b * HH + h) * NN + n) * NN + m] = val;
        }
    }
}

// ---------------------------------------------------------------------------
extern "C" void kernel_launch(void* const* d_in, const int* in_sizes, int n_in,
                              void* d_out, int out_size, void* d_ws, size_t ws_size,
                              hipStream_t stream) {
    const float* x    = (const float*)d_in[0];
    const int*   adj  = (const int*)d_in[1];
    const float* W    = (const float*)d_in[2];
    const float* a    = (const float*)d_in[3];
    const float* Wp   = (const float*)d_in[4];
    const float* bias = (const float*)d_in[5];

    float* out       = (float*)d_out;
    float* alpha_out = out + (size_t)BB * NN * DD;

    // Scratch inside the fp32 alpha region (268 MB; overwritten LAST by k_alpha):
    //   hT      bf16 [B*H][D][N] at alpha floats [0, 4.19M)  (8.39M ushorts)
    //   out_scr fp32 [B*H][N][D] at alpha floats [4.19M, 8.39M)
    unsigned short* hT = (unsigned short*)alpha_out;
    float* out_scr     = alpha_out + (size_t)BB * HH * NN * DD;

    float* ws  = (float*)d_ws;      // 528 KB of stats only
    float* wsv = ws;
    float* wdv = wsv + HH * DD;
    float* s_  = wdv + HH * DD;
    float* d_  = s_ + BB * HH * NN;
    float* M_  = d_ + BB * HH * NN;
    float* Li_ = M_ + BB * HH * NN;

    k_wvec<<<HH, 128, 0, stream>>>(W, a, wsv, wdv);
    k_sd<<<BB * NN / 64, 256, 0, stream>>>(x, wsv, wdv, s_, d_);
    k_h<<<BB * HH * (NN / 32), 256, 0, stream>>>(x, W, hT);
    k_stats<<<BB * NN, 256, 0, stream>>>(adj, s_, d_, M_, Li_);
    k_attn_mfma<<<BB * HH * (NN / 64), 256, 0, stream>>>(adj, s_, d_, M_, Li_,
                                                         hT, out_scr);
    k_proj<<<BB * (NN / 16), 256, 0, stream>>>(out_scr, Wp, bias, out);
    k_alpha<<<BB * NN, 256, 0, stream>>>(adj, s_, d_, M_, Li_, alpha_out);
}